// Round 1
// baseline (575.543 us; speedup 1.0000x reference)
//
#include <hip/hip_runtime.h>
#include <hip/hip_bf16.h>

#define NE 8
#define HD 256
#define NT 128
#define NTHREADS 512

typedef __attribute__((ext_vector_type(8))) short short8;
typedef __attribute__((ext_vector_type(4))) float f32x4;

__device__ __forceinline__ unsigned short f2bf(float f) {
    union { float f; unsigned int u; } v; v.f = f;
    return (unsigned short)((v.u + 0x7FFFu + ((v.u >> 16) & 1u)) >> 16);
}
__device__ __forceinline__ float bf2f(unsigned short s) {
    union { unsigned int u; float f; } v; v.u = ((unsigned int)s) << 16;
    return v.f;
}
// XOR-swizzled LDS index (element units); keeps 8-element (16B) chunks intact.
__device__ __forceinline__ int swz(int row, int col) {
    return row * HD + (col ^ ((row & 7) << 3));
}

// One-time prep: W[e][k][n] fp32 -> Wt[e][n][k] bf16 (contiguous-K B-fragments).
__global__ void prep_weights(const float* __restrict__ W1, const float* __restrict__ W2,
                             unsigned short* __restrict__ W1t, unsigned short* __restrict__ W2t) {
    int idx = blockIdx.x * blockDim.x + threadIdx.x;
    if (idx >= NE * HD * HD) return;
    int nn = idx & 255;          // coalesced read dim
    int kk = (idx >> 8) & 255;
    int e  = idx >> 16;
    W1t[(e * HD + nn) * HD + kk] = f2bf(W1[(e * HD + kk) * HD + nn]);
    W2t[(e * HD + nn) * HD + kk] = f2bf(W2[(e * HD + kk) * HD + nn]);
}

// One 256x256 GEMM layer + bias + relu: Aout = relu(Ain * W + b).
// Ain/Aout: LDS [NT][HD] bf16, XOR-swizzled. Wt: global bf16 [HD out][HD k].
__device__ __forceinline__ void gemm_relu_layer(
    const unsigned short* Ain, const unsigned short* __restrict__ Wt,
    const float* __restrict__ bias, unsigned short* Aout, int w, int lane)
{
    const int l15 = lane & 15;
    const int kg  = lane >> 4;           // k-group 0..3
    f32x4 acc[8][2];
    #pragma unroll
    for (int mt = 0; mt < 8; ++mt)
        #pragma unroll
        for (int nt = 0; nt < 2; ++nt)
            acc[mt][nt] = (f32x4){0.f, 0.f, 0.f, 0.f};

    #pragma unroll
    for (int ks = 0; ks < 8; ++ks) {     // K = 256 in steps of 32
        const int k0 = ks * 32 + kg * 8;
        short8 bfrag[2];
        #pragma unroll
        for (int nt = 0; nt < 2; ++nt) {
            int col = (w * 32) + nt * 16 + l15;
            bfrag[nt] = *(const short8*)(Wt + col * HD + k0);   // 16B L2-hit load
        }
        #pragma unroll
        for (int mt = 0; mt < 8; ++mt) {
            int row = mt * 16 + l15;
            short8 afrag = *(const short8*)(Ain + swz(row, k0)); // ds_read_b128
            #pragma unroll
            for (int nt = 0; nt < 2; ++nt)
                acc[mt][nt] = __builtin_amdgcn_mfma_f32_16x16x32_bf16(
                    afrag, bfrag[nt], acc[mt][nt], 0, 0, 0);
        }
    }
    // Epilogue: C/D layout col=lane&15, row=(lane>>4)*4+r (m89-verified).
    #pragma unroll
    for (int nt = 0; nt < 2; ++nt) {
        const int col = (w * 32) + nt * 16 + l15;
        const float bb = bias[col];
        #pragma unroll
        for (int mt = 0; mt < 8; ++mt)
            #pragma unroll
            for (int r = 0; r < 4; ++r) {
                int row = mt * 16 + kg * 4 + r;
                Aout[swz(row, col)] = f2bf(fmaxf(acc[mt][nt][r] + bb, 0.f));
            }
    }
}

__global__ __launch_bounds__(NTHREADS, 2) void moe_fused(
    const float* __restrict__ coords, int npts,
    const float* __restrict__ W0, const float* __restrict__ b0,
    const unsigned short* __restrict__ W1t, const float* __restrict__ b1,
    const unsigned short* __restrict__ W2t, const float* __restrict__ b2,
    const float* __restrict__ W3, const float* __restrict__ b3,
    float* __restrict__ out)
{
    __shared__ __align__(16) unsigned short Abuf[NT * HD];  // 64 KB
    __shared__ __align__(16) unsigned short Bbuf[NT * HD];  // 64 KB
    __shared__ float cbuf[NT * 3];

    const int t = threadIdx.x;
    const int lane = t & 63;
    const int w = t >> 6;
    const int p0 = blockIdx.x * NT;

    if (t < NT * 3) {
        int idx = p0 * 3 + t;
        int lim = npts * 3 - 1;
        cbuf[t] = coords[idx < lim ? idx : lim];   // clamp: in-bounds, tail masked on store
    }

    float runmax = -3.4e38f;

    for (int e = 0; e < NE; ++e) {
        __syncthreads();   // protects Abuf/cbuf (prev expert's layer3 reads / initial load)
        // ---- layer 0: 3 -> 256, fp32 VALU ----
        {
            const int j = t & 255;
            const int rbase = (t >> 8) * (NT / 2);
            const float w0x = W0[(e * 3 + 0) * HD + j];
            const float w0y = W0[(e * 3 + 1) * HD + j];
            const float w0z = W0[(e * 3 + 2) * HD + j];
            const float bb  = b0[e * HD + j];
            #pragma unroll 4
            for (int pp = 0; pp < NT / 2; ++pp) {
                int row = rbase + pp;
                float h = fmaxf(cbuf[row*3]*w0x + cbuf[row*3+1]*w0y + cbuf[row*3+2]*w0z + bb, 0.f);
                Abuf[swz(row, j)] = f2bf(h);
            }
        }
        __syncthreads();
        // ---- layer 1: Abuf -> Bbuf ----
        gemm_relu_layer(Abuf, W1t + e * HD * HD, b1 + e * HD, Bbuf, w, lane);
        __syncthreads();
        // ---- layer 2: Bbuf -> Abuf ----
        gemm_relu_layer(Bbuf, W2t + e * HD * HD, b2 + e * HD, Abuf, w, lane);
        __syncthreads();
        // ---- layer 3: 256 -> 1, fp32 VALU + quad shuffle-reduce; running max ----
        {
            const int p = t >> 2;       // 128 points, 4 threads/point
            const int part = t & 3;
            const float* w3 = W3 + e * HD;
            float s = 0.f;
            #pragma unroll
            for (int kk = 0; kk < 64; kk += 8) {
                int k = part * 64 + kk;
                short8 hv = *(const short8*)(Abuf + swz(p, k));
                const float* w3k = w3 + k;
                #pragma unroll
                for (int j = 0; j < 8; ++j)
                    s += bf2f((unsigned short)hv[j]) * w3k[j];
            }
            s += __shfl_xor(s, 1);
            s += __shfl_xor(s, 2);
            runmax = fmaxf(runmax, s + b3[e]);
        }
    }
    if ((t & 3) == 0) {
        int p = p0 + (t >> 2);
        if (p < npts) out[p] = runmax;
    }
}

extern "C" void kernel_launch(void* const* d_in, const int* in_sizes, int n_in,
                              void* d_out, int out_size, void* d_ws, size_t ws_size,
                              hipStream_t stream) {
    const float* coords = (const float*)d_in[0];
    const float* W0 = (const float*)d_in[1];
    const float* b0 = (const float*)d_in[2];
    const float* W1 = (const float*)d_in[3];
    const float* b1 = (const float*)d_in[4];
    const float* W2 = (const float*)d_in[5];
    const float* b2 = (const float*)d_in[6];
    const float* W3 = (const float*)d_in[7];
    const float* b3 = (const float*)d_in[8];
    const int npts = in_sizes[0] / 3;

    unsigned short* W1t = (unsigned short*)d_ws;               // 1 MB
    unsigned short* W2t = W1t + NE * HD * HD;                  // 1 MB

    prep_weights<<<(NE * HD * HD + 255) / 256, 256, 0, stream>>>(W1, W2, W1t, W2t);

    int nblocks = (npts + NT - 1) / NT;
    moe_fused<<<nblocks, NTHREADS, 0, stream>>>(
        coords, npts, W0, b0, W1t, b1, W2t, b2, W3, b3, (float*)d_out);
}